// Round 1
// baseline (6184.404 us; speedup 1.0000x reference)
//
#include <hip/hip_runtime.h>

// QLSTM: T=512, B=64, D=512, H=512.
// Phase A: precompute gx[tb][2560] = bf16( X@[Wx|Wr]^T + bias )  (gates x-part + residual)
// Phase B: persistent 32-block kernel, 512 steps, hand-rolled device barrier.
//          Block jb owns h_out slice [jb*16, jb*16+16) for all 4 gates; c in regs.

typedef __bf16         bfrag8 __attribute__((ext_vector_type(8)));
typedef float          f32x4v __attribute__((ext_vector_type(4)));
typedef unsigned short u16x8  __attribute__((ext_vector_type(8)));

#define N_TB    32768   // T*B
#define GXW     2560    // 4*512 gate rows + 512 residual rows
#define OUT_STK 16777216
#define OUT_HX  16777216
#define OUT_CX  16809984

__device__ __forceinline__ float bf2f(unsigned short u) {
  unsigned int x = ((unsigned int)u) << 16;
  return __builtin_bit_cast(float, x);
}
__device__ __forceinline__ unsigned short f2bf(float f) {
  unsigned int x = __builtin_bit_cast(unsigned int, f);
  x = x + 0x7FFFu + ((x >> 16) & 1u);   // RNE
  return (unsigned short)(x >> 16);
}
__device__ __forceinline__ float sigf(float x) {
  x = fminf(fmaxf(x, -30.f), 30.f);
  return 1.f / (1.f + __expf(-x));
}
__device__ __forceinline__ float tanh_f(float x) {
  x = fminf(fmaxf(x, -15.f), 15.f);
  float e = __expf(-2.f * x);
  return (1.f - e) / (1.f + e);
}

// ---------- K1: f32 -> bf16 convert (inputs -> X) ----------
__global__ void cvt_kernel(const float* __restrict__ in, unsigned short* __restrict__ out) {
  int i = (blockIdx.x * 256 + threadIdx.x) * 4;
  float4 v = *(const float4*)(in + i);
  ushort4 o = make_ushort4(f2bf(v.x), f2bf(v.y), f2bf(v.z), f2bf(v.w));
  *(ushort4*)(out + i) = o;
}

// ---------- K2: weight repack f32->bf16 ----------
// Wc [2560][512]: rows 0..2047 = W_gate[:, :512]; rows 2048..2559 = W_r
// Whx [2048][512]: W_gate[:, 512:]
__global__ void repack_kernel(const float* __restrict__ Wf, const float* __restrict__ Wi,
                              const float* __restrict__ Wg, const float* __restrict__ Wo,
                              const float* __restrict__ Wr,
                              const float* __restrict__ bfp, const float* __restrict__ bip,
                              const float* __restrict__ bgp, const float* __restrict__ bop,
                              const float* __restrict__ brp,
                              unsigned short* __restrict__ Wc, unsigned short* __restrict__ Whx,
                              float* __restrict__ bias) {
  int tid = blockIdx.x * 256 + threadIdx.x;
  if (tid < 262144) {                    // gate rows: 2048 rows x 128 quads
    int row = tid >> 7;
    int k4  = (tid & 127) * 4;
    int g = row >> 9, h = row & 511;
    const float* W = (g == 0) ? Wf : (g == 1) ? Wi : (g == 2) ? Wg : Wo;
    float4 a = *(const float4*)(W + (size_t)h * 1024 + k4);
    float4 b = *(const float4*)(W + (size_t)h * 1024 + 512 + k4);
    *(ushort4*)(Wc  + (size_t)row * 512 + k4) = make_ushort4(f2bf(a.x), f2bf(a.y), f2bf(a.z), f2bf(a.w));
    *(ushort4*)(Whx + (size_t)row * 512 + k4) = make_ushort4(f2bf(b.x), f2bf(b.y), f2bf(b.z), f2bf(b.w));
  } else if (tid < 327680) {             // residual rows
    int t2 = tid - 262144;
    int row = t2 >> 7;
    int k4  = (t2 & 127) * 4;
    float4 a = *(const float4*)(Wr + (size_t)row * 512 + k4);
    *(ushort4*)(Wc + (size_t)(2048 + row) * 512 + k4) =
        make_ushort4(f2bf(a.x), f2bf(a.y), f2bf(a.z), f2bf(a.w));
  }
  if (tid < 2560) {
    float v;
    if      (tid <  512) v = bfp[tid];
    else if (tid < 1024) v = bip[tid - 512];
    else if (tid < 1536) v = bgp[tid - 1024];
    else if (tid < 2048) v = bop[tid - 1536];
    else                 v = brp[tid - 2048];
    bias[tid] = v;
  }
}

// ---------- K3: GEMM  C[n][m] = bf16( sum_k A[m][k]*B[n][k] + bias[m] ) ----------
// A = Wc [2560][512], B = X [32768][512], C = gx [32768][2560]
__global__ __launch_bounds__(256)
void gemm_kernel(const unsigned short* __restrict__ A, const unsigned short* __restrict__ B,
                 const float* __restrict__ bias, unsigned short* __restrict__ C) {
  const int bm = blockIdx.x;       // 0..19
  const int bn = blockIdx.y;       // 0..255
  const int tid = threadIdx.x;
  const int lane = tid & 63;
  const int w = tid >> 6;
  const int wm = w & 1, wn = w >> 1;
  const int col = lane & 15, q = lane >> 4;

  __shared__ unsigned short As[128 * 64] __attribute__((aligned(16)));
  __shared__ unsigned short Bs[128 * 64] __attribute__((aligned(16)));

  f32x4v acc[4][4] = {};

  for (int kt = 0; kt < 8; ++kt) {
    __syncthreads();
    #pragma unroll
    for (int p = 0; p < 4; ++p) {
      int idx = p * 256 + tid;          // 16B granule id
      int row = idx >> 3, gc = idx & 7;
      *(u16x8*)(&As[idx * 8]) = *(const u16x8*)(A + (size_t)(bm * 128 + row) * 512 + kt * 64 + gc * 8);
      *(u16x8*)(&Bs[idx * 8]) = *(const u16x8*)(B + (size_t)(bn * 128 + row) * 512 + kt * 64 + gc * 8);
    }
    __syncthreads();
    #pragma unroll
    for (int kk = 0; kk < 2; ++kk) {
      bfrag8 af[4], bfr[4];
      #pragma unroll
      for (int mt = 0; mt < 4; ++mt)
        af[mt] = *(const bfrag8*)(&As[(wm * 64 + mt * 16 + col) * 64 + kk * 32 + q * 8]);
      #pragma unroll
      for (int nt = 0; nt < 4; ++nt)
        bfr[nt] = *(const bfrag8*)(&Bs[(wn * 64 + nt * 16 + col) * 64 + kk * 32 + q * 8]);
      #pragma unroll
      for (int mt = 0; mt < 4; ++mt)
        #pragma unroll
        for (int nt = 0; nt < 4; ++nt)
          acc[mt][nt] = __builtin_amdgcn_mfma_f32_16x16x32_bf16(af[mt], bfr[nt], acc[mt][nt], 0, 0, 0);
    }
  }
  #pragma unroll
  for (int mt = 0; mt < 4; ++mt) {
    const int m0 = bm * 128 + wm * 64 + mt * 16 + q * 4;
    const float4 b4 = *(const float4*)(bias + m0);
    #pragma unroll
    for (int nt = 0; nt < 4; ++nt) {
      const int n = bn * 128 + wn * 64 + nt * 16 + col;
      f32x4v v = acc[mt][nt];
      ushort4 o = make_ushort4(f2bf(v[0] + b4.x), f2bf(v[1] + b4.y),
                               f2bf(v[2] + b4.z), f2bf(v[3] + b4.w));
      *(ushort4*)(C + (size_t)n * GXW + m0) = o;
    }
  }
}

// ---------- K4: persistent recurrent kernel ----------
// 32 blocks x 256 threads. Block jb owns h_out [jb*16, jb*16+16).
// Wave w: gp=w&1 (gates {2gp,2gp+1}), mh=w>>1 (batch rows mh*32..mh*32+31).
__global__ __launch_bounds__(256, 1)
void recur_kernel(const unsigned short* __restrict__ Whx, const unsigned short* __restrict__ gx,
                  unsigned short* __restrict__ hbuf, int* flags, float* __restrict__ out) {
  const int jb = blockIdx.x;
  const int tid = threadIdx.x;
  const int lane = tid & 63;
  const int w = tid >> 6;
  const int gp = w & 1;
  const int mh = w >> 1;
  const int col = lane & 15;
  const int q = lane >> 4;

  __shared__ float S[4][64][16] __attribute__((aligned(16)));

  // Static recurrent-weight fragments: 2 gates x 16 k-tiles, held in VGPRs all 512 steps.
  bfrag8 Bf[2][16];
  #pragma unroll
  for (int g2 = 0; g2 < 2; ++g2) {
    const int gate = gp * 2 + g2;
    const unsigned short* wp = Whx + (size_t)(gate * 512 + jb * 16 + col) * 512 + q * 8;
    #pragma unroll
    for (int kk = 0; kk < 16; ++kk)
      Bf[g2][kk] = *(const bfrag8*)(wp + kk * 32);
  }

  // Update-phase mapping: thread -> (batch ub, 4 cols starting at ucg)
  const int ub = tid >> 2;
  const int ucg = (tid & 3) * 4;
  float c4[4] = {0.f, 0.f, 0.f, 0.f};

  // prefetch gx/res for t=0
  ushort4 gxv[4], rv;
  {
    const unsigned short* g0 = gx + (size_t)ub * GXW + jb * 16 + ucg;
    #pragma unroll
    for (int gg = 0; gg < 4; ++gg) gxv[gg] = *(const ushort4*)(g0 + gg * 512);
    rv = *(const ushort4*)(g0 + 2048);
  }

  for (int t = 0; t < 512; ++t) {
    if (t > 0) {
      if (tid < 32) {
        while (__hip_atomic_load(flags + tid, __ATOMIC_RELAXED, __HIP_MEMORY_SCOPE_AGENT) < t)
          __builtin_amdgcn_s_sleep(1);
      }
      __syncthreads();
      __threadfence();   // acquire: invalidate stale L2 so hbuf reads are fresh (cross-XCD)
    }

    // S = h_{t-1} @ Whx_slice^T   (A-frags from hbuf, B-frags static)
    const unsigned short* hrd = hbuf + (t & 1) * 32768;
    bfrag8 Af[2][16];
    #pragma unroll
    for (int mt = 0; mt < 2; ++mt) {
      const unsigned short* ap = hrd + (size_t)(mh * 32 + mt * 16 + col) * 512 + q * 8;
      #pragma unroll
      for (int kk = 0; kk < 16; ++kk)
        Af[mt][kk] = *(const bfrag8*)(ap + kk * 32);
    }
    f32x4v acc[2][2] = {};
    #pragma unroll
    for (int kk = 0; kk < 16; ++kk)
      #pragma unroll
      for (int mt = 0; mt < 2; ++mt)
        #pragma unroll
        for (int g2 = 0; g2 < 2; ++g2)
          acc[mt][g2] = __builtin_amdgcn_mfma_f32_16x16x32_bf16(Af[mt][kk], Bf[g2][kk], acc[mt][g2], 0, 0, 0);

    #pragma unroll
    for (int mt = 0; mt < 2; ++mt)
      #pragma unroll
      for (int g2 = 0; g2 < 2; ++g2) {
        const int gate = gp * 2 + g2;
        const int b0 = mh * 32 + mt * 16 + q * 4;
        #pragma unroll
        for (int r = 0; r < 4; ++r)
          S[gate][b0 + r][col] = acc[mt][g2][r];
      }
    __syncthreads();

    // elementwise gate/update (all 256 threads)
    float pre[4][4];
    #pragma unroll
    for (int gg = 0; gg < 4; ++gg) {
      float4 sv = *(const float4*)&S[gg][ub][ucg];
      pre[gg][0] = sv.x + bf2f(gxv[gg].x);
      pre[gg][1] = sv.y + bf2f(gxv[gg].y);
      pre[gg][2] = sv.z + bf2f(gxv[gg].z);
      pre[gg][3] = sv.w + bf2f(gxv[gg].w);
    }
    float rres[4] = {bf2f(rv.x), bf2f(rv.y), bf2f(rv.z), bf2f(rv.w)};
    float hv[4];
    #pragma unroll
    for (int j = 0; j < 4; ++j) {
      float fg = sigf(pre[0][j]);
      float ig = sigf(pre[1][j]);
      float gg = tanh_f(pre[2][j]);
      float og = sigf(pre[3][j]);
      c4[j] = fg * c4[j] + ig * gg;
      hv[j] = og * tanh_f(c4[j]) + rres[j];
    }

    float4 h4 = make_float4(hv[0], hv[1], hv[2], hv[3]);
    *(float4*)(out + (size_t)t * 32768 + ub * 512 + jb * 16 + ucg) = h4;
    ushort4 hb4 = make_ushort4(f2bf(hv[0]), f2bf(hv[1]), f2bf(hv[2]), f2bf(hv[3]));
    *(ushort4*)(hbuf + ((t + 1) & 1) * 32768 + ub * 512 + jb * 16 + ucg) = hb4;

    if (t == 511) {
      *(float4*)(out + OUT_HX + ub * 512 + jb * 16 + ucg) = h4;
      *(float4*)(out + OUT_CX + ub * 512 + jb * 16 + ucg) = make_float4(c4[0], c4[1], c4[2], c4[3]);
    } else {
      // prefetch gx/res for t+1 (latency hides under fence+barrier+MFMA)
      const unsigned short* gn = gx + (size_t)((t + 1) * 64 + ub) * GXW + jb * 16 + ucg;
      #pragma unroll
      for (int gg = 0; gg < 4; ++gg) gxv[gg] = *(const ushort4*)(gn + gg * 512);
      rv = *(const ushort4*)(gn + 2048);
    }

    __threadfence();   // release: flush h stores to device coherence point
    __syncthreads();
    if (tid == 0)
      __hip_atomic_store(flags + jb, t + 1, __ATOMIC_RELAXED, __HIP_MEMORY_SCOPE_AGENT);
  }
}

extern "C" void kernel_launch(void* const* d_in, const int* in_sizes, int n_in,
                              void* d_out, int out_size, void* d_ws, size_t ws_size,
                              hipStream_t stream) {
  const float* inputs = (const float*)d_in[0];
  const float* Wf = (const float*)d_in[1];
  const float* bf_ = (const float*)d_in[2];
  const float* Wi = (const float*)d_in[3];
  const float* bi_ = (const float*)d_in[4];
  const float* Wg = (const float*)d_in[5];
  const float* bg_ = (const float*)d_in[6];
  const float* Wo = (const float*)d_in[7];
  const float* bo_ = (const float*)d_in[8];
  const float* Wr = (const float*)d_in[9];
  const float* br_ = (const float*)d_in[10];
  float* out = (float*)d_out;

  // workspace layout (all 16B-aligned)
  unsigned short* X    = (unsigned short*)d_ws;        // 16777216 el
  unsigned short* Wc   = X + 16777216;                 // 1310720 el
  unsigned short* Whx  = Wc + 1310720;                 // 1048576 el
  float*          bias = (float*)(Whx + 1048576);      // 2560 el
  unsigned short* gx   = (unsigned short*)(bias + 2560);  // 83886080 el
  unsigned short* hbuf = gx + 83886080;                // 65536 el
  int*            flags = (int*)(hbuf + 65536);        // 32 el
  const size_t ws_needed = 206186624;
  if (ws_size < ws_needed) return;   // fail visibly rather than corrupt

  hipMemsetAsync(hbuf, 0, 65536 * 2 + 32 * 4, stream);   // h0 = 0, flags = 0

  cvt_kernel<<<16384, 256, 0, stream>>>(inputs, X);
  repack_kernel<<<1280, 256, 0, stream>>>(Wf, Wi, Wg, Wo, Wr, bf_, bi_, bg_, bo_, br_,
                                          Wc, Whx, bias);
  gemm_kernel<<<dim3(20, 256), 256, 0, stream>>>(Wc, X, bias, gx);
  recur_kernel<<<32, 256, 0, stream>>>(Whx, gx, hbuf, flags, out);
}

// Round 2
// 3316.697 us; speedup vs baseline: 1.8646x; 1.8646x over previous
//
#include <hip/hip_runtime.h>

// QLSTM: T=512, B=64, D=512, H=512.
// Phase A: precompute gx[tb][2560] = bf16( X@[Wx|Wr]^T + bias )  (gates x-part + residual)
// Phase B: persistent 32-block kernel, 512 steps.
//   Sync redesign (R2): no __threadfence (wbl2/inv was 11.6us/step). Instead:
//   - h published via relaxed AGENT-scope atomic stores (sc0/sc1 write-through to L3)
//   - s_waitcnt vmcnt(0) + flag store (relaxed agent atomic)
//   - consumers poll flags (agent atomic loads), then stage hbuf->LDS via agent
//     atomic dword loads (bypass stale L1/L2, read coherent L3). MFMA reads LDS.

typedef __bf16         bfrag8 __attribute__((ext_vector_type(8)));
typedef float          f32x4v __attribute__((ext_vector_type(4)));
typedef unsigned short u16x8  __attribute__((ext_vector_type(8)));

#define N_TB    32768   // T*B
#define GXW     2560    // 4*512 gate rows + 512 residual rows
#define OUT_HX  16777216
#define OUT_CX  16809984

__device__ __forceinline__ float bf2f(unsigned short u) {
  unsigned int x = ((unsigned int)u) << 16;
  return __builtin_bit_cast(float, x);
}
__device__ __forceinline__ unsigned short f2bf(float f) {
  unsigned int x = __builtin_bit_cast(unsigned int, f);
  x = x + 0x7FFFu + ((x >> 16) & 1u);   // RNE
  return (unsigned short)(x >> 16);
}
__device__ __forceinline__ float sigf(float x) {
  x = fminf(fmaxf(x, -30.f), 30.f);
  return 1.f / (1.f + __expf(-x));
}
__device__ __forceinline__ float tanh_f(float x) {
  x = fminf(fmaxf(x, -15.f), 15.f);
  float e = __expf(-2.f * x);
  return (1.f - e) / (1.f + e);
}

// ---------- K1: f32 -> bf16 convert (inputs -> X) ----------
__global__ void cvt_kernel(const float* __restrict__ in, unsigned short* __restrict__ out) {
  int i = (blockIdx.x * 256 + threadIdx.x) * 4;
  float4 v = *(const float4*)(in + i);
  ushort4 o = make_ushort4(f2bf(v.x), f2bf(v.y), f2bf(v.z), f2bf(v.w));
  *(ushort4*)(out + i) = o;
}

// ---------- K2: weight repack f32->bf16 ----------
__global__ void repack_kernel(const float* __restrict__ Wf, const float* __restrict__ Wi,
                              const float* __restrict__ Wg, const float* __restrict__ Wo,
                              const float* __restrict__ Wr,
                              const float* __restrict__ bfp, const float* __restrict__ bip,
                              const float* __restrict__ bgp, const float* __restrict__ bop,
                              const float* __restrict__ brp,
                              unsigned short* __restrict__ Wc, unsigned short* __restrict__ Whx,
                              float* __restrict__ bias) {
  int tid = blockIdx.x * 256 + threadIdx.x;
  if (tid < 262144) {                    // gate rows: 2048 rows x 128 quads
    int row = tid >> 7;
    int k4  = (tid & 127) * 4;
    int g = row >> 9, h = row & 511;
    const float* W = (g == 0) ? Wf : (g == 1) ? Wi : (g == 2) ? Wg : Wo;
    float4 a = *(const float4*)(W + (size_t)h * 1024 + k4);
    float4 b = *(const float4*)(W + (size_t)h * 1024 + 512 + k4);
    *(ushort4*)(Wc  + (size_t)row * 512 + k4) = make_ushort4(f2bf(a.x), f2bf(a.y), f2bf(a.z), f2bf(a.w));
    *(ushort4*)(Whx + (size_t)row * 512 + k4) = make_ushort4(f2bf(b.x), f2bf(b.y), f2bf(b.z), f2bf(b.w));
  } else if (tid < 327680) {             // residual rows
    int t2 = tid - 262144;
    int row = t2 >> 7;
    int k4  = (t2 & 127) * 4;
    float4 a = *(const float4*)(Wr + (size_t)row * 512 + k4);
    *(ushort4*)(Wc + (size_t)(2048 + row) * 512 + k4) =
        make_ushort4(f2bf(a.x), f2bf(a.y), f2bf(a.z), f2bf(a.w));
  }
  if (tid < 2560) {
    float v;
    if      (tid <  512) v = bfp[tid];
    else if (tid < 1024) v = bip[tid - 512];
    else if (tid < 1536) v = bgp[tid - 1024];
    else if (tid < 2048) v = bop[tid - 1536];
    else                 v = brp[tid - 2048];
    bias[tid] = v;
  }
}

// ---------- K3: GEMM  C[n][m] = bf16( sum_k A[m][k]*B[n][k] + bias[m] ) ----------
__global__ __launch_bounds__(256)
void gemm_kernel(const unsigned short* __restrict__ A, const unsigned short* __restrict__ B,
                 const float* __restrict__ bias, unsigned short* __restrict__ C) {
  const int bm = blockIdx.x;       // 0..19
  const int bn = blockIdx.y;       // 0..255
  const int tid = threadIdx.x;
  const int lane = tid & 63;
  const int w = tid >> 6;
  const int wm = w & 1, wn = w >> 1;
  const int col = lane & 15, q = lane >> 4;

  __shared__ unsigned short As[128 * 64] __attribute__((aligned(16)));
  __shared__ unsigned short Bs[128 * 64] __attribute__((aligned(16)));

  f32x4v acc[4][4] = {};

  for (int kt = 0; kt < 8; ++kt) {
    __syncthreads();
    #pragma unroll
    for (int p = 0; p < 4; ++p) {
      int idx = p * 256 + tid;          // 16B granule id
      int row = idx >> 3, gc = idx & 7;
      *(u16x8*)(&As[idx * 8]) = *(const u16x8*)(A + (size_t)(bm * 128 + row) * 512 + kt * 64 + gc * 8);
      *(u16x8*)(&Bs[idx * 8]) = *(const u16x8*)(B + (size_t)(bn * 128 + row) * 512 + kt * 64 + gc * 8);
    }
    __syncthreads();
    #pragma unroll
    for (int kk = 0; kk < 2; ++kk) {
      bfrag8 af[4], bfr[4];
      #pragma unroll
      for (int mt = 0; mt < 4; ++mt)
        af[mt] = *(const bfrag8*)(&As[(wm * 64 + mt * 16 + col) * 64 + kk * 32 + q * 8]);
      #pragma unroll
      for (int nt = 0; nt < 4; ++nt)
        bfr[nt] = *(const bfrag8*)(&Bs[(wn * 64 + nt * 16 + col) * 64 + kk * 32 + q * 8]);
      #pragma unroll
      for (int mt = 0; mt < 4; ++mt)
        #pragma unroll
        for (int nt = 0; nt < 4; ++nt)
          acc[mt][nt] = __builtin_amdgcn_mfma_f32_16x16x32_bf16(af[mt], bfr[nt], acc[mt][nt], 0, 0, 0);
    }
  }
  #pragma unroll
  for (int mt = 0; mt < 4; ++mt) {
    const int m0 = bm * 128 + wm * 64 + mt * 16 + q * 4;
    const float4 b4 = *(const float4*)(bias + m0);
    #pragma unroll
    for (int nt = 0; nt < 4; ++nt) {
      const int n = bn * 128 + wn * 64 + nt * 16 + col;
      f32x4v v = acc[mt][nt];
      ushort4 o = make_ushort4(f2bf(v[0] + b4.x), f2bf(v[1] + b4.y),
                               f2bf(v[2] + b4.z), f2bf(v[3] + b4.w));
      *(ushort4*)(C + (size_t)n * GXW + m0) = o;
    }
  }
}

// ---------- K4: persistent recurrent kernel ----------
// 32 blocks x 256 threads. Block jb owns h_out [jb*16, jb*16+16).
__global__ __launch_bounds__(256, 1)
void recur_kernel(const unsigned short* __restrict__ Whx, const unsigned short* __restrict__ gx,
                  unsigned short* __restrict__ hbuf, int* flags, float* __restrict__ out) {
  const int jb = blockIdx.x;
  const int tid = threadIdx.x;
  const int lane = tid & 63;
  const int w = tid >> 6;
  const int gp = w & 1;
  const int mh = w >> 1;
  const int col = lane & 15;
  const int q = lane >> 4;

  __shared__ float S[4][64][16] __attribute__((aligned(16)));
  __shared__ unsigned short Hs[64][520] __attribute__((aligned(16)));  // +8 pad: 2-way b128 (free)

  // Static recurrent-weight fragments: 2 gates x 16 k-tiles, in VGPRs for all 512 steps.
  bfrag8 Bf[2][16];
  #pragma unroll
  for (int g2 = 0; g2 < 2; ++g2) {
    const int gate = gp * 2 + g2;
    const unsigned short* wp = Whx + (size_t)(gate * 512 + jb * 16 + col) * 512 + q * 8;
    #pragma unroll
    for (int kk = 0; kk < 16; ++kk)
      Bf[g2][kk] = *(const bfrag8*)(wp + kk * 32);
  }

  // Update-phase mapping: thread -> (batch ub, 4 cols starting at ucg)
  const int ub = tid >> 2;
  const int ucg = (tid & 3) * 4;
  float c4[4] = {0.f, 0.f, 0.f, 0.f};

  // prefetch gx/res for t=0
  ushort4 gxv[4], rv;
  {
    const unsigned short* g0 = gx + (size_t)ub * GXW + jb * 16 + ucg;
    #pragma unroll
    for (int gg = 0; gg < 4; ++gg) gxv[gg] = *(const ushort4*)(g0 + gg * 512);
    rv = *(const ushort4*)(g0 + 2048);
  }

  for (int t = 0; t < 512; ++t) {
    if (t > 0) {
      if (tid < 32) {
        while (__hip_atomic_load(flags + tid, __ATOMIC_RELAXED, __HIP_MEMORY_SCOPE_AGENT) < t) {
        }
      }
      __syncthreads();
    }

    // Stage h_{t-1} (64 KB) into LDS via agent-scope (coherent) dword loads.
    {
      const unsigned int* hsrc = (const unsigned int*)(hbuf + (t & 1) * 32768);
      #pragma unroll
      for (int i = 0; i < 64; i += 8) {
        unsigned int tmp[8];
        #pragma unroll
        for (int j = 0; j < 8; ++j)
          tmp[j] = __hip_atomic_load(hsrc + (i + j) * 256 + tid,
                                     __ATOMIC_RELAXED, __HIP_MEMORY_SCOPE_AGENT);
        #pragma unroll
        for (int j = 0; j < 8; ++j)
          *((unsigned int*)&Hs[i + j][0] + tid) = tmp[j];
      }
    }
    __syncthreads();

    // S = h_{t-1} @ Whx_slice^T  (A-frags from LDS, B-frags static)
    bfrag8 Af[2][16];
    #pragma unroll
    for (int mt = 0; mt < 2; ++mt) {
      const unsigned short* ap = &Hs[mh * 32 + mt * 16 + col][q * 8];
      #pragma unroll
      for (int kk = 0; kk < 16; ++kk)
        Af[mt][kk] = *(const bfrag8*)(ap + kk * 32);
    }
    f32x4v acc[2][2] = {};
    #pragma unroll
    for (int kk = 0; kk < 16; ++kk)
      #pragma unroll
      for (int mt = 0; mt < 2; ++mt)
        #pragma unroll
        for (int g2 = 0; g2 < 2; ++g2)
          acc[mt][g2] = __builtin_amdgcn_mfma_f32_16x16x32_bf16(Af[mt][kk], Bf[g2][kk], acc[mt][g2], 0, 0, 0);

    #pragma unroll
    for (int mt = 0; mt < 2; ++mt)
      #pragma unroll
      for (int g2 = 0; g2 < 2; ++g2) {
        const int gate = gp * 2 + g2;
        const int b0 = mh * 32 + mt * 16 + q * 4;
        #pragma unroll
        for (int r = 0; r < 4; ++r)
          S[gate][b0 + r][col] = acc[mt][g2][r];
      }
    __syncthreads();

    // elementwise gate/update (all 256 threads)
    float pre[4][4];
    #pragma unroll
    for (int gg = 0; gg < 4; ++gg) {
      float4 sv = *(const float4*)&S[gg][ub][ucg];
      pre[gg][0] = sv.x + bf2f(gxv[gg].x);
      pre[gg][1] = sv.y + bf2f(gxv[gg].y);
      pre[gg][2] = sv.z + bf2f(gxv[gg].z);
      pre[gg][3] = sv.w + bf2f(gxv[gg].w);
    }
    float rres[4] = {bf2f(rv.x), bf2f(rv.y), bf2f(rv.z), bf2f(rv.w)};
    float hv[4];
    #pragma unroll
    for (int j = 0; j < 4; ++j) {
      float fg = sigf(pre[0][j]);
      float ig = sigf(pre[1][j]);
      float gg = tanh_f(pre[2][j]);
      float og = sigf(pre[3][j]);
      c4[j] = fg * c4[j] + ig * gg;
      hv[j] = og * tanh_f(c4[j]) + rres[j];
    }
    float4 h4 = make_float4(hv[0], hv[1], hv[2], hv[3]);

    if (t < 511) {
      // Publish h_t: agent-scope 8B atomic store (write-through), drain, flag.
      ushort4 hb4 = make_ushort4(f2bf(hv[0]), f2bf(hv[1]), f2bf(hv[2]), f2bf(hv[3]));
      union { ushort4 u4; unsigned long long u64; } pk;
      pk.u4 = hb4;
      __hip_atomic_store((unsigned long long*)(hbuf + ((t + 1) & 1) * 32768 + ub * 512 + jb * 16 + ucg),
                         pk.u64, __ATOMIC_RELAXED, __HIP_MEMORY_SCOPE_AGENT);
      asm volatile("s_waitcnt vmcnt(0)" ::: "memory");
      __syncthreads();
      if (tid == 0)
        __hip_atomic_store(flags + jb, t + 1, __ATOMIC_RELAXED, __HIP_MEMORY_SCOPE_AGENT);
    }

    // Non-critical-path stores after publish.
    *(float4*)(out + (size_t)t * 32768 + ub * 512 + jb * 16 + ucg) = h4;

    if (t == 511) {
      *(float4*)(out + OUT_HX + ub * 512 + jb * 16 + ucg) = h4;
      *(float4*)(out + OUT_CX + ub * 512 + jb * 16 + ucg) = make_float4(c4[0], c4[1], c4[2], c4[3]);
    } else {
      // prefetch gx/res for t+1 (arrives during next poll)
      const unsigned short* gn = gx + (size_t)((t + 1) * 64 + ub) * GXW + jb * 16 + ucg;
      #pragma unroll
      for (int gg = 0; gg < 4; ++gg) gxv[gg] = *(const ushort4*)(gn + gg * 512);
      rv = *(const ushort4*)(gn + 2048);
    }
  }
}

extern "C" void kernel_launch(void* const* d_in, const int* in_sizes, int n_in,
                              void* d_out, int out_size, void* d_ws, size_t ws_size,
                              hipStream_t stream) {
  const float* inputs = (const float*)d_in[0];
  const float* Wf = (const float*)d_in[1];
  const float* bf_ = (const float*)d_in[2];
  const float* Wi = (const float*)d_in[3];
  const float* bi_ = (const float*)d_in[4];
  const float* Wg = (const float*)d_in[5];
  const float* bg_ = (const float*)d_in[6];
  const float* Wo = (const float*)d_in[7];
  const float* bo_ = (const float*)d_in[8];
  const float* Wr = (const float*)d_in[9];
  const float* br_ = (const float*)d_in[10];
  float* out = (float*)d_out;

  // workspace layout (all 16B-aligned)
  unsigned short* X    = (unsigned short*)d_ws;        // 16777216 el
  unsigned short* Wc   = X + 16777216;                 // 1310720 el
  unsigned short* Whx  = Wc + 1310720;                 // 1048576 el
  float*          bias = (float*)(Whx + 1048576);      // 2560 el
  unsigned short* gx   = (unsigned short*)(bias + 2560);  // 83886080 el
  unsigned short* hbuf = gx + 83886080;                // 65536 el
  int*            flags = (int*)(hbuf + 65536);        // 32 el
  const size_t ws_needed = 206186624;
  if (ws_size < ws_needed) return;   // fail visibly rather than corrupt

  hipMemsetAsync(hbuf, 0, 65536 * 2 + 32 * 4, stream);   // h0 = 0 (both slots), flags = 0

  cvt_kernel<<<16384, 256, 0, stream>>>(inputs, X);
  repack_kernel<<<1280, 256, 0, stream>>>(Wf, Wi, Wg, Wo, Wr, bf_, bi_, bg_, bo_, br_,
                                          Wc, Whx, bias);
  gemm_kernel<<<dim3(20, 256), 256, 0, stream>>>(Wc, X, bias, gx);
  recur_kernel<<<32, 256, 0, stream>>>(Whx, gx, hbuf, flags, out);
}

// Round 3
// 2498.154 us; speedup vs baseline: 2.4756x; 1.3277x over previous
//
#include <hip/hip_runtime.h>

// QLSTM: T=512, B=64, D=512, H=512.
// Phase A: precompute gx[tb][2560] = bf16( X@[Wx|Wr]^T + bias )  (gates x-part + residual)
// Phase B: persistent 32-block kernel, 512 steps.
//   R2: replaced __threadfence (wbl2/inv, 11.6us/step) with agent-scope atomics.
//   R3: staging was 8 serialized L3 round-trips (5.6us/step). Now: 16x
//       global_load_dwordx4 sc0 sc1 issued back-to-back, ONE vmcnt drain,
//       then b128 LDS writes. Plus S padded [64][20] to kill 4-way ds_write
//       bank conflict (b0 always %4==0 -> all lanes hit banks 0-15).

typedef __bf16         bfrag8 __attribute__((ext_vector_type(8)));
typedef float          f32x4v __attribute__((ext_vector_type(4)));
typedef unsigned short u16x8  __attribute__((ext_vector_type(8)));
typedef int            v4i    __attribute__((ext_vector_type(4)));

#define N_TB    32768   // T*B
#define GXW     2560    // 4*512 gate rows + 512 residual rows
#define OUT_HX  16777216
#define OUT_CX  16809984

__device__ __forceinline__ float bf2f(unsigned short u) {
  unsigned int x = ((unsigned int)u) << 16;
  return __builtin_bit_cast(float, x);
}
__device__ __forceinline__ unsigned short f2bf(float f) {
  unsigned int x = __builtin_bit_cast(unsigned int, f);
  x = x + 0x7FFFu + ((x >> 16) & 1u);   // RNE
  return (unsigned short)(x >> 16);
}
__device__ __forceinline__ float sigf(float x) {
  x = fminf(fmaxf(x, -30.f), 30.f);
  return 1.f / (1.f + __expf(-x));
}
__device__ __forceinline__ float tanh_f(float x) {
  x = fminf(fmaxf(x, -15.f), 15.f);
  float e = __expf(-2.f * x);
  return (1.f - e) / (1.f + e);
}

// ---------- K1: f32 -> bf16 convert (inputs -> X) ----------
__global__ void cvt_kernel(const float* __restrict__ in, unsigned short* __restrict__ out) {
  int i = (blockIdx.x * 256 + threadIdx.x) * 4;
  float4 v = *(const float4*)(in + i);
  ushort4 o = make_ushort4(f2bf(v.x), f2bf(v.y), f2bf(v.z), f2bf(v.w));
  *(ushort4*)(out + i) = o;
}

// ---------- K2: weight repack f32->bf16 ----------
__global__ void repack_kernel(const float* __restrict__ Wf, const float* __restrict__ Wi,
                              const float* __restrict__ Wg, const float* __restrict__ Wo,
                              const float* __restrict__ Wr,
                              const float* __restrict__ bfp, const float* __restrict__ bip,
                              const float* __restrict__ bgp, const float* __restrict__ bop,
                              const float* __restrict__ brp,
                              unsigned short* __restrict__ Wc, unsigned short* __restrict__ Whx,
                              float* __restrict__ bias) {
  int tid = blockIdx.x * 256 + threadIdx.x;
  if (tid < 262144) {                    // gate rows: 2048 rows x 128 quads
    int row = tid >> 7;
    int k4  = (tid & 127) * 4;
    int g = row >> 9, h = row & 511;
    const float* W = (g == 0) ? Wf : (g == 1) ? Wi : (g == 2) ? Wg : Wo;
    float4 a = *(const float4*)(W + (size_t)h * 1024 + k4);
    float4 b = *(const float4*)(W + (size_t)h * 1024 + 512 + k4);
    *(ushort4*)(Wc  + (size_t)row * 512 + k4) = make_ushort4(f2bf(a.x), f2bf(a.y), f2bf(a.z), f2bf(a.w));
    *(ushort4*)(Whx + (size_t)row * 512 + k4) = make_ushort4(f2bf(b.x), f2bf(b.y), f2bf(b.z), f2bf(b.w));
  } else if (tid < 327680) {             // residual rows
    int t2 = tid - 262144;
    int row = t2 >> 7;
    int k4  = (t2 & 127) * 4;
    float4 a = *(const float4*)(Wr + (size_t)row * 512 + k4);
    *(ushort4*)(Wc + (size_t)(2048 + row) * 512 + k4) =
        make_ushort4(f2bf(a.x), f2bf(a.y), f2bf(a.z), f2bf(a.w));
  }
  if (tid < 2560) {
    float v;
    if      (tid <  512) v = bfp[tid];
    else if (tid < 1024) v = bip[tid - 512];
    else if (tid < 1536) v = bgp[tid - 1024];
    else if (tid < 2048) v = bop[tid - 1536];
    else                 v = brp[tid - 2048];
    bias[tid] = v;
  }
}

// ---------- K3: GEMM  C[n][m] = bf16( sum_k A[m][k]*B[n][k] + bias[m] ) ----------
__global__ __launch_bounds__(256)
void gemm_kernel(const unsigned short* __restrict__ A, const unsigned short* __restrict__ B,
                 const float* __restrict__ bias, unsigned short* __restrict__ C) {
  const int bm = blockIdx.x;       // 0..19
  const int bn = blockIdx.y;       // 0..255
  const int tid = threadIdx.x;
  const int lane = tid & 63;
  const int w = tid >> 6;
  const int wm = w & 1, wn = w >> 1;
  const int col = lane & 15, q = lane >> 4;

  __shared__ unsigned short As[128 * 64] __attribute__((aligned(16)));
  __shared__ unsigned short Bs[128 * 64] __attribute__((aligned(16)));

  f32x4v acc[4][4] = {};

  for (int kt = 0; kt < 8; ++kt) {
    __syncthreads();
    #pragma unroll
    for (int p = 0; p < 4; ++p) {
      int idx = p * 256 + tid;          // 16B granule id
      int row = idx >> 3, gc = idx & 7;
      *(u16x8*)(&As[idx * 8]) = *(const u16x8*)(A + (size_t)(bm * 128 + row) * 512 + kt * 64 + gc * 8);
      *(u16x8*)(&Bs[idx * 8]) = *(const u16x8*)(B + (size_t)(bn * 128 + row) * 512 + kt * 64 + gc * 8);
    }
    __syncthreads();
    #pragma unroll
    for (int kk = 0; kk < 2; ++kk) {
      bfrag8 af[4], bfr[4];
      #pragma unroll
      for (int mt = 0; mt < 4; ++mt)
        af[mt] = *(const bfrag8*)(&As[(wm * 64 + mt * 16 + col) * 64 + kk * 32 + q * 8]);
      #pragma unroll
      for (int nt = 0; nt < 4; ++nt)
        bfr[nt] = *(const bfrag8*)(&Bs[(wn * 64 + nt * 16 + col) * 64 + kk * 32 + q * 8]);
      #pragma unroll
      for (int mt = 0; mt < 4; ++mt)
        #pragma unroll
        for (int nt = 0; nt < 4; ++nt)
          acc[mt][nt] = __builtin_amdgcn_mfma_f32_16x16x32_bf16(af[mt], bfr[nt], acc[mt][nt], 0, 0, 0);
    }
  }
  #pragma unroll
  for (int mt = 0; mt < 4; ++mt) {
    const int m0 = bm * 128 + wm * 64 + mt * 16 + q * 4;
    const float4 b4 = *(const float4*)(bias + m0);
    #pragma unroll
    for (int nt = 0; nt < 4; ++nt) {
      const int n = bn * 128 + wn * 64 + nt * 16 + col;
      f32x4v v = acc[mt][nt];
      ushort4 o = make_ushort4(f2bf(v[0] + b4.x), f2bf(v[1] + b4.y),
                               f2bf(v[2] + b4.z), f2bf(v[3] + b4.w));
      *(ushort4*)(C + (size_t)n * GXW + m0) = o;
    }
  }
}

// ---------- K4: persistent recurrent kernel ----------
// 32 blocks x 256 threads. Block jb owns h_out [jb*16, jb*16+16).
__global__ __launch_bounds__(256, 1)
void recur_kernel(const unsigned short* __restrict__ Whx, const unsigned short* __restrict__ gx,
                  unsigned short* __restrict__ hbuf, int* flags, float* __restrict__ out) {
  const int jb = blockIdx.x;
  const int tid = threadIdx.x;
  const int lane = tid & 63;
  const int w = tid >> 6;
  const int gp = w & 1;
  const int mh = w >> 1;
  const int col = lane & 15;
  const int q = lane >> 4;

  __shared__ float S[4][64][20] __attribute__((aligned(16)));           // stride 20: 2-way banks
  __shared__ unsigned short Hs[64][520] __attribute__((aligned(16)));   // +8 pad: 2-way b128

  // Static recurrent-weight fragments: 2 gates x 16 k-tiles, in VGPRs for all 512 steps.
  bfrag8 Bf[2][16];
  #pragma unroll
  for (int g2 = 0; g2 < 2; ++g2) {
    const int gate = gp * 2 + g2;
    const unsigned short* wp = Whx + (size_t)(gate * 512 + jb * 16 + col) * 512 + q * 8;
    #pragma unroll
    for (int kk = 0; kk < 16; ++kk)
      Bf[g2][kk] = *(const bfrag8*)(wp + kk * 32);
  }

  // Update-phase mapping: thread -> (batch ub, 4 cols starting at ucg)
  const int ub = tid >> 2;
  const int ucg = (tid & 3) * 4;
  float c4[4] = {0.f, 0.f, 0.f, 0.f};

  // prefetch gx/res for t=0
  ushort4 gxv[4], rv;
  {
    const unsigned short* g0 = gx + (size_t)ub * GXW + jb * 16 + ucg;
    #pragma unroll
    for (int gg = 0; gg < 4; ++gg) gxv[gg] = *(const ushort4*)(g0 + gg * 512);
    rv = *(const ushort4*)(g0 + 2048);
  }

  for (int t = 0; t < 512; ++t) {
    if (t > 0) {
      if (tid < 32) {
        while (__hip_atomic_load(flags + tid, __ATOMIC_RELAXED, __HIP_MEMORY_SCOPE_AGENT) < t) {
        }
      }
      __syncthreads();
    }

    // Stage h_{t-1} (64 KB) into LDS: all 16 coherent 16B loads issued
    // back-to-back (ONE L3 round-trip), single drain, then b128 LDS writes.
    {
      const char* hsrc = (const char*)(hbuf + (t & 1) * 32768);
      v4i tmp[16];
      #pragma unroll
      for (int i = 0; i < 16; ++i) {
        const char* p = hsrc + (size_t)(i * 256 + tid) * 16;
        asm volatile("global_load_dwordx4 %0, %1, off sc0 sc1"
                     : "=v"(tmp[i]) : "v"(p) : "memory");
      }
      asm volatile("s_waitcnt vmcnt(0)" ::: "memory");
      #pragma unroll
      for (int i = 0; i < 16; ++i) {
        int idx = i * 256 + tid;                       // 16B granule id in 64KB
        *(v4i*)((char*)&Hs[0][0] + (size_t)(idx >> 6) * 1040 + (idx & 63) * 16) = tmp[i];
      }
    }
    __syncthreads();

    // S = h_{t-1} @ Whx_slice^T  (A-frags from LDS, B-frags static)
    bfrag8 Af[2][16];
    #pragma unroll
    for (int mt = 0; mt < 2; ++mt) {
      const unsigned short* ap = &Hs[mh * 32 + mt * 16 + col][q * 8];
      #pragma unroll
      for (int kk = 0; kk < 16; ++kk)
        Af[mt][kk] = *(const bfrag8*)(ap + kk * 32);
    }
    f32x4v acc[2][2] = {};
    #pragma unroll
    for (int kk = 0; kk < 16; ++kk)
      #pragma unroll
      for (int mt = 0; mt < 2; ++mt)
        #pragma unroll
        for (int g2 = 0; g2 < 2; ++g2)
          acc[mt][g2] = __builtin_amdgcn_mfma_f32_16x16x32_bf16(Af[mt][kk], Bf[g2][kk], acc[mt][g2], 0, 0, 0);

    #pragma unroll
    for (int mt = 0; mt < 2; ++mt)
      #pragma unroll
      for (int g2 = 0; g2 < 2; ++g2) {
        const int gate = gp * 2 + g2;
        const int b0 = mh * 32 + mt * 16 + q * 4;
        #pragma unroll
        for (int r = 0; r < 4; ++r)
          S[gate][b0 + r][col] = acc[mt][g2][r];
      }
    __syncthreads();

    // elementwise gate/update (all 256 threads)
    float pre[4][4];
    #pragma unroll
    for (int gg = 0; gg < 4; ++gg) {
      float4 sv = *(const float4*)&S[gg][ub][ucg];
      pre[gg][0] = sv.x + bf2f(gxv[gg].x);
      pre[gg][1] = sv.y + bf2f(gxv[gg].y);
      pre[gg][2] = sv.z + bf2f(gxv[gg].z);
      pre[gg][3] = sv.w + bf2f(gxv[gg].w);
    }
    float rres[4] = {bf2f(rv.x), bf2f(rv.y), bf2f(rv.z), bf2f(rv.w)};
    float hv[4];
    #pragma unroll
    for (int j = 0; j < 4; ++j) {
      float fg = sigf(pre[0][j]);
      float ig = sigf(pre[1][j]);
      float gg = tanh_f(pre[2][j]);
      float og = sigf(pre[3][j]);
      c4[j] = fg * c4[j] + ig * gg;
      hv[j] = og * tanh_f(c4[j]) + rres[j];
    }
    float4 h4 = make_float4(hv[0], hv[1], hv[2], hv[3]);

    if (t < 511) {
      // Publish h_t: agent-scope 8B atomic store (write-through), drain, flag.
      ushort4 hb4 = make_ushort4(f2bf(hv[0]), f2bf(hv[1]), f2bf(hv[2]), f2bf(hv[3]));
      union { ushort4 u4; unsigned long long u64; } pk;
      pk.u4 = hb4;
      __hip_atomic_store((unsigned long long*)(hbuf + ((t + 1) & 1) * 32768 + ub * 512 + jb * 16 + ucg),
                         pk.u64, __ATOMIC_RELAXED, __HIP_MEMORY_SCOPE_AGENT);
      asm volatile("s_waitcnt vmcnt(0)" ::: "memory");
      __syncthreads();
      if (tid == 0)
        __hip_atomic_store(flags + jb, t + 1, __ATOMIC_RELAXED, __HIP_MEMORY_SCOPE_AGENT);
    }

    // Non-critical-path stores after publish.
    *(float4*)(out + (size_t)t * 32768 + ub * 512 + jb * 16 + ucg) = h4;

    if (t == 511) {
      *(float4*)(out + OUT_HX + ub * 512 + jb * 16 + ucg) = h4;
      *(float4*)(out + OUT_CX + ub * 512 + jb * 16 + ucg) = make_float4(c4[0], c4[1], c4[2], c4[3]);
    } else {
      // prefetch gx/res for t+1 (arrives during next poll)
      const unsigned short* gn = gx + (size_t)((t + 1) * 64 + ub) * GXW + jb * 16 + ucg;
      #pragma unroll
      for (int gg = 0; gg < 4; ++gg) gxv[gg] = *(const ushort4*)(gn + gg * 512);
      rv = *(const ushort4*)(gn + 2048);
    }
  }
}

extern "C" void kernel_launch(void* const* d_in, const int* in_sizes, int n_in,
                              void* d_out, int out_size, void* d_ws, size_t ws_size,
                              hipStream_t stream) {
  const float* inputs = (const float*)d_in[0];
  const float* Wf = (const float*)d_in[1];
  const float* bf_ = (const float*)d_in[2];
  const float* Wi = (const float*)d_in[3];
  const float* bi_ = (const float*)d_in[4];
  const float* Wg = (const float*)d_in[5];
  const float* bg_ = (const float*)d_in[6];
  const float* Wo = (const float*)d_in[7];
  const float* bo_ = (const float*)d_in[8];
  const float* Wr = (const float*)d_in[9];
  const float* br_ = (const float*)d_in[10];
  float* out = (float*)d_out;

  // workspace layout (all 16B-aligned)
  unsigned short* X    = (unsigned short*)d_ws;        // 16777216 el
  unsigned short* Wc   = X + 16777216;                 // 1310720 el
  unsigned short* Whx  = Wc + 1310720;                 // 1048576 el
  float*          bias = (float*)(Whx + 1048576);      // 2560 el
  unsigned short* gx   = (unsigned short*)(bias + 2560);  // 83886080 el
  unsigned short* hbuf = gx + 83886080;                // 65536 el
  int*            flags = (int*)(hbuf + 65536);        // 32 el
  const size_t ws_needed = 206186624;
  if (ws_size < ws_needed) return;   // fail visibly rather than corrupt

  hipMemsetAsync(hbuf, 0, 65536 * 2 + 32 * 4, stream);   // h0 = 0 (both slots), flags = 0

  cvt_kernel<<<16384, 256, 0, stream>>>(inputs, X);
  repack_kernel<<<1280, 256, 0, stream>>>(Wf, Wi, Wg, Wo, Wr, bf_, bi_, bg_, bo_, br_,
                                          Wc, Whx, bias);
  gemm_kernel<<<dim3(20, 256), 256, 0, stream>>>(Wc, X, bias, gx);
  recur_kernel<<<32, 256, 0, stream>>>(Whx, gx, hbuf, flags, out);
}